// Round 12
// baseline (248.386 us; speedup 1.0000x reference)
//
#include <hip/hip_runtime.h>
#include <stdint.h>

// ---------------------------------------------------------------------------
// Fused LSTM cell, round 12: ZERO-BARRIER main via per-wave-private LDS.
//  prep_all: xb[131072][128] bf16 (pad, k127=1.0), hb[131072][256] bf16,
//            Bt fragment blob (bias @ k127). Unchanged from r11.
//  lstm_main: 256 thr (4 waves: wr=wid>>1, wc=wid&1), tile 128 x 128.
//    Each wave owns a PRIVATE 16 KiB LDS slice: A dbuf 2x4K (its 64 rows),
//    B dbuf 2x4K (its 4 gate-fragment units). 8 gl_lds/wave/stage, 2-deep,
//    VMW(8) self-sync -- NO s_barrier in the entire kernel. Step order:
//    VMW(8); COMPUTE(S) (ds_reads all consumed by MFMAs -> retired);
//    STAGE(S+2) (safe overwrite). Waves free-run and de-phase, so CU-level
//    MFMA/LDS/VMEM usage interleaves instead of pulsing in convoy.
// ---------------------------------------------------------------------------

typedef short bf16x8 __attribute__((ext_vector_type(8)));
typedef float f32x4  __attribute__((ext_vector_type(4)));

#define HDIM   256
#define INDIM  100
#define NROWS  131072
// d_ws layout (ushort offsets): Bt @0 (768 KiB), xb @1 MiB, hb @34 MiB
#define BT_OFF 0
#define XB_OFF (1048576 / 2)
#define HB_OFF (35651584 / 2)

__device__ __forceinline__ float fexp(float x) {
  return __builtin_amdgcn_exp2f(x * 1.44269504088896340736f);
}
__device__ __forceinline__ float frcp(float x) { return __builtin_amdgcn_rcpf(x); }
__device__ __forceinline__ float sigm(float x) { return frcp(1.0f + fexp(-x)); }
__device__ __forceinline__ float tanh_fast(float x) {
  return 1.0f - 2.0f * frcp(1.0f + fexp(2.0f * x));
}
__device__ __forceinline__ unsigned short f2bf_rne(float f) {
  union { float f; uint32_t u; } v; v.f = f;
  return (unsigned short)((v.u + 0x7FFFu + ((v.u >> 16) & 1u)) >> 16);
}
__device__ __forceinline__ void gl16(const void* g, void* l) {
  __builtin_amdgcn_global_load_lds(
      (const __attribute__((address_space(1))) unsigned int*)g,
      (__attribute__((address_space(3))) unsigned int*)l, 16, 0, 0);
}
#define VMW(N) asm volatile("s_waitcnt vmcnt(" #N ")" ::: "memory")

// ---- prep: 3 jobs (unchanged) ---------------------------------------------
__global__ void prep_all(const float* __restrict__ X, const float* __restrict__ Hin,
                         const float* __restrict__ Wx, const float* __restrict__ Wh,
                         const float* __restrict__ bxp, const float* __restrict__ bhp,
                         unsigned short* __restrict__ ws) {
  const int b = blockIdx.x, tid = threadIdx.x;
  if (b < 8192) {                        // ---- x -> xb[131072][128] ----
    const int t   = b * 256 + tid;
    const int row = t >> 4, k0 = (t & 15) * 8;
    const float* xp = X + (size_t)row * INDIM;
    float4 lo = make_float4(0.f, 0.f, 0.f, 0.f);
    float4 hi = make_float4(0.f, 0.f, 0.f, 0.f);
    if (k0 + 4 <= INDIM) lo = *reinterpret_cast<const float4*>(xp + k0);
    if (k0 + 8 <= INDIM) hi = *reinterpret_cast<const float4*>(xp + k0 + 4);
    float va[8] = {lo.x, lo.y, lo.z, lo.w, hi.x, hi.y, hi.z, hi.w};
    unsigned short o[8];
#pragma unroll
    for (int e = 0; e < 8; ++e) {
      const int k = k0 + e;
      const float f = (k < INDIM) ? va[e] : (k == 127 ? 1.0f : 0.0f);
      o[e] = f2bf_rne(f);
    }
    *reinterpret_cast<bf16x8*>(ws + XB_OFF + (size_t)row * 128 + k0) =
        *reinterpret_cast<bf16x8*>(o);
  } else if (b < 24576) {                // ---- h -> hb[131072][256] ----
    const int t   = (b - 8192) * 256 + tid;
    const int row = t >> 5, k0 = (t & 31) * 8;
    const float* hp = Hin + (size_t)row * HDIM + k0;
    const float4 lo = *reinterpret_cast<const float4*>(hp);
    const float4 hi = *reinterpret_cast<const float4*>(hp + 4);
    unsigned short o[8] = {f2bf_rne(lo.x), f2bf_rne(lo.y), f2bf_rne(lo.z),
                           f2bf_rne(lo.w), f2bf_rne(hi.x), f2bf_rne(hi.y),
                           f2bf_rne(hi.z), f2bf_rne(hi.w)};
    *reinterpret_cast<bf16x8*>(ws + HB_OFF + (size_t)row * 256 + k0) =
        *reinterpret_cast<bf16x8*>(o);
  } else {                               // ---- W -> Bt blob (bias @ k127) --
    const int unit = (b - 24576) * 4 + (tid >> 6);   // 0..767
    const int lane = tid & 63;
    const int kst  = unit % 12;
    const int fidb = unit / 12;
    const int bn   = fidb >> 3, fid = fidb & 7;
    const int g    = fid >> 1,  wc  = fid & 1;
    const int wcol = g * HDIM + bn * 32 + wc * 16 + (lane & 15);
    const int kb   = kst * 32 + (lane >> 4) * 8;
    unsigned short v[8];
#pragma unroll
    for (int e = 0; e < 8; ++e) {
      const int k = kb + e;              // 0..383
      float f = 0.0f;
      if (k < INDIM)     f = Wx[(size_t)k * 1024 + wcol];
      else if (k == 127) f = bxp[wcol] + bhp[wcol];
      else if (k >= 128) f = Wh[(size_t)(k - 128) * 1024 + wcol];
      v[e] = f2bf_rne(f);
    }
    *reinterpret_cast<bf16x8*>(ws + BT_OFF + (size_t)unit * 512 + lane * 8) =
        *reinterpret_cast<bf16x8*>(v);
  }
}

// ---- main -----------------------------------------------------------------
__global__ __launch_bounds__(256, 2)
void lstm_main(const unsigned short* __restrict__ ws,
               const float* __restrict__ Cin, float* __restrict__ out)
{
  __shared__ unsigned char smem[65536];  // 4 waves x (A 2x4K | B 2x4K)

  const int tid  = threadIdx.x;
  const int orig = blockIdx.x;           // 0..8191 (%8==0 -> bijective)
  const int lg   = ((orig & 7) << 10) | (orig >> 3);
  const int mt   = lg >> 3;              // M tile 0..1023 (128 rows)
  const int bn   = lg & 7;               // N tile 0..7 (32 H-cols)

  const int lane = tid & 63;
  const int l15  = lane & 15;
  const int kq   = lane >> 4;
  const int wid  = tid >> 6;             // 0..3
  const int wr   = wid >> 1;             // 0..1: 64-row group
  const int wc   = wid & 1;              // 0..1: 16-hcol half
  const int ch   = bn * 32 + wc * 16 + l15;
  const int sx   = (l15 >> 1) & 3;       // read-side XOR (== (row>>1)&3)

  const unsigned short* xb = ws + XB_OFF;
  const unsigned short* hb = ws + HB_OFF;
  const unsigned short* Bt = ws + BT_OFF;

  // per-wave private LDS slice
  char* const wls = (char*)smem + wid * 16384;   // A@0 (2x4K), B@8192 (2x4K)

  // staging sources: this wave's 64 A-rows (4 gl16) + 4 B-units (4 gl16)
  const unsigned short* xsrc[4];
  const unsigned short* hsrc[4];
  const unsigned short* bsrc[4];
#pragma unroll
  for (int j = 0; j < 4; ++j) {
    const int cj = j * 64 + lane;                // 0..255
    const int r  = cj >> 2;                      // wave-local row 0..63
    const int sc = (cj & 3) ^ ((r >> 1) & 3);    // pre-swizzled chunk
    const int gr = mt * 128 + wr * 64 + r;       // global row
    xsrc[j] = xb + (size_t)gr * 128 + sc * 8;
    hsrc[j] = hb + (size_t)gr * 256 + sc * 8;
    bsrc[j] = Bt + (size_t)((bn * 8 + j * 2 + wc) * 12) * 512 + lane * 8;
  }

  f32x4 acc[4][4];
#pragma unroll
  for (int m = 0; m < 4; ++m)
#pragma unroll
    for (int g = 0; g < 4; ++g)
#pragma unroll
      for (int e = 0; e < 4; ++e) acc[m][g][e] = 0.0f;

  float cvv[4][4];

  auto STAGE = [&](int T) {              // 8 gl_lds into buffer T&1
    char* Ad = wls + (T & 1) * 4096;
    char* Bd = wls + 8192 + (T & 1) * 4096;
    if (T < 4) {
#pragma unroll
      for (int j = 0; j < 4; ++j) gl16(xsrc[j] + T * 32, Ad + j * 1024);
    } else {
#pragma unroll
      for (int j = 0; j < 4; ++j) gl16(hsrc[j] + (T - 4) * 32, Ad + j * 1024);
    }
#pragma unroll
    for (int g = 0; g < 4; ++g) gl16(bsrc[g] + T * 512, Bd + g * 1024);
  };

  auto COMPUTE = [&](int S) {
    const unsigned short* Ab = (const unsigned short*)(wls + (S & 1) * 4096);
    const unsigned short* Bb =
        (const unsigned short*)(wls + 8192 + (S & 1) * 4096);
    bf16x8 afr[4], bfr[4];
#pragma unroll
    for (int m = 0; m < 4; ++m)
      afr[m] = *reinterpret_cast<const bf16x8*>(
          Ab + (m * 16 + l15) * 32 + ((kq ^ sx) * 8));
#pragma unroll
    for (int g = 0; g < 4; ++g)
      bfr[g] = *reinterpret_cast<const bf16x8*>(Bb + g * 512 + lane * 8);
    __builtin_amdgcn_s_setprio(1);
#pragma unroll
    for (int m = 0; m < 4; ++m)
#pragma unroll
      for (int g = 0; g < 4; ++g)
        acc[m][g] = __builtin_amdgcn_mfma_f32_16x16x32_bf16(
            afr[m], bfr[g], acc[m][g], 0, 0, 0);
    __builtin_amdgcn_s_setprio(0);
  };

  // prologue: 2 stages (16 gl_lds) in flight
  STAGE(0);
  STAGE(1);

  // Per-wave FIFO (8 gl_lds/stage, no barriers):
  //  step S: VMW -> COMPUTE(S) (all ds_reads consumed => buffer S&1 free)
  //          -> STAGE(S+2) overwrites it safely.
  //  Steady VMW(8); C-prefetch (16 loads) issued at end of step 9:
  //  S=10 -> VMW(24); S=11 -> VMW(16); epilogue VMW(0).
#define STEP(S, KN)                                               \
  do {                                                            \
    VMW(KN);                                                      \
    COMPUTE(S);                                                   \
    if ((S) + 2 < 12) STAGE((S) + 2);                             \
    if ((S) == 9) {                                               \
      const float* cb =                                           \
          Cin + ((size_t)mt * 128 + wr * 64 + kq * 4) * HDIM + ch;\
      _Pragma("unroll")                                           \
      for (int m = 0; m < 4; ++m)                                 \
        _Pragma("unroll")                                         \
        for (int e = 0; e < 4; ++e)                               \
          cvv[m][e] = __builtin_nontemporal_load(                 \
              cb + (size_t)(m * 16 + e) * HDIM);                  \
    }                                                             \
  } while (0)

  STEP(0, 8);  STEP(1, 8);  STEP(2, 8);  STEP(3, 8);
  STEP(4, 8);  STEP(5, 8);  STEP(6, 8);  STEP(7, 8);
  STEP(8, 8);  STEP(9, 8);  STEP(10, 24); STEP(11, 16);
#undef STEP

  VMW(0);                                // C prefetch landed

  // ---- epilogue: bias folded in acc; lane-local gate combine -------------
  float* op  = out + ((size_t)mt * 128 + wr * 64 + kq * 4) * HDIM + ch;
  float* op2 = op + (size_t)NROWS * HDIM;
#pragma unroll
  for (int m = 0; m < 4; ++m) {
#pragma unroll
    for (int e = 0; e < 4; ++e) {
      const float pi = acc[m][0][e];
      const float pf = acc[m][1][e];
      const float pg = acc[m][2][e];
      const float po = acc[m][3][e];
      const float ig = sigm(pi), fg = sigm(pf);
      const float gg = tanh_fast(pg), og = sigm(po);
      const float co = fg * cvv[m][e] + ig * gg;
      const float ho = og * tanh_fast(co);
      __builtin_nontemporal_store(co, op  + (size_t)(m * 16 + e) * HDIM);
      __builtin_nontemporal_store(ho, op2 + (size_t)(m * 16 + e) * HDIM);
    }
  }
}

extern "C" void kernel_launch(void* const* d_in, const int* in_sizes, int n_in,
                              void* d_out, int out_size, void* d_ws, size_t ws_size,
                              hipStream_t stream) {
  const float* x  = (const float*)d_in[0];
  const float* C  = (const float*)d_in[1];
  const float* h  = (const float*)d_in[2];
  const float* Wx = (const float*)d_in[3];
  const float* Wh = (const float*)d_in[4];
  const float* bx = (const float*)d_in[5];
  const float* bh = (const float*)d_in[6];
  float* o = (float*)d_out;
  unsigned short* ws = (unsigned short*)d_ws;   // ~98 MiB used

  prep_all<<<dim3(24768), dim3(256), 0, stream>>>(x, h, Wx, Wh, bx, bh, ws);
  lstm_main<<<dim3(8192), dim3(256), 0, stream>>>(ws, C, o);
}